// Round 16
// baseline (478.205 us; speedup 1.0000x reference)
//
#include <hip/hip_runtime.h>
#include <hip/hip_bf16.h>

#define N_NODES   50000
#define N_EDGES   500000
#define FDIM      128
#define N_CLASSES 32
#define N_GRAPHS  64

// ---------------------------------------------------------------------------
// Preprocessing: degree count, prefix scan over PADDED degrees (pad to x4),
// CSR fill + dummy self-edge padding (w=0).
// ---------------------------------------------------------------------------

__global__ void deg_kernel(const int* __restrict__ dst, int* __restrict__ deg, int E) {
    int e = blockIdx.x * blockDim.x + threadIdx.x;
    if (e < E) atomicAdd(&deg[dst[e]], 1);
}

__global__ void scan_partial(const int* __restrict__ deg, int* __restrict__ part,
                             float* __restrict__ dis, int n) {
    __shared__ int s[512];
    int t = threadIdx.x;
    int i = blockIdx.x * 512 + t;
    int d = (i < n) ? deg[i] : 0;
    if (i < n) dis[i] = rsqrtf((float)d + 1.0f);
    s[t] = (i < n) ? ((d + 3) & ~3) : 0;
    __syncthreads();
    for (int o = 256; o > 0; o >>= 1) {
        if (t < o) s[t] += s[t + o];
        __syncthreads();
    }
    if (t == 0) part[blockIdx.x] = s[0];
}

__global__ void scan_offsets(int* part, int nb) {
    if (blockIdx.x == 0 && threadIdx.x == 0) {
        int acc = 0;
        for (int i = 0; i < nb; i++) { int v = part[i]; part[i] = acc; acc += v; }
    }
}

__global__ void scan_final(const int* __restrict__ deg, const int* __restrict__ part,
                           int* __restrict__ rowptr, int n) {
    __shared__ int s[512];
    int t = threadIdx.x;
    int i = blockIdx.x * 512 + t;
    int v = (i < n) ? ((deg[i] + 3) & ~3) : 0;
    s[t] = v;
    __syncthreads();
    for (int o = 1; o < 512; o <<= 1) {
        int x = (t >= o) ? s[t - o] : 0;
        __syncthreads();
        s[t] += x;
        __syncthreads();
    }
    if (i < n) rowptr[i] = part[blockIdx.x] + s[t] - v;   // exclusive (padded)
}

__global__ void fill_csr(const int* __restrict__ src, const int* __restrict__ dst,
                         const int* __restrict__ rowptr, int* __restrict__ fill,
                         const float* __restrict__ dis,
                         int2* __restrict__ csr_sw, int E) {
    int e = blockIdx.x * blockDim.x + threadIdx.x;
    if (e >= E) return;
    int d = dst[e], s = src[e];
    int pos = rowptr[d] + atomicAdd(&fill[d], 1);
    float w = dis[s] * dis[d];
    csr_sw[pos] = make_int2(s, __float_as_int(w));
}

__global__ void pad_csr(const int* __restrict__ deg, const int* __restrict__ rowptr,
                        int2* __restrict__ csr_sw, int n) {
    int v = blockIdx.x * blockDim.x + threadIdx.x;
    if (v >= n) return;
    int d = deg[v], dp = (d + 3) & ~3;
    int base = rowptr[v];
    for (int i = d; i < dp; i++) csr_sw[base + i] = make_int2(v, 0);
}

// ---------------------------------------------------------------------------
// Fused GCN layer: OUT = relu( ((A + ns*I) H) W + b )
// 256t, 8 nodes/wave gather, group-swizzled xs (R15), and DOUBLE-BUFFERED ws:
// per 16-k chunk: issue next-chunk W loads (regs) -> 16 k of FMA (hides the
// load latency) -> LDS write -> one barrier. LDS = 16 + 16 = 32 KB.
// ---------------------------------------------------------------------------

#define PGATH(I, EBASE)                                                         \
    int2 p##I = sw[(EBASE) + 2 * (I) + half];                                   \
    float4 m##I = *(const float4*)(H + (size_t)p##I.x * FDIM + q * 4);

#define PFMA(I)                                                                 \
    {                                                                           \
        float w_ = __int_as_float(p##I.y);                                      \
        acc.x = fmaf(w_, m##I.x, acc.x);                                        \
        acc.y = fmaf(w_, m##I.y, acc.y);                                        \
        acc.z = fmaf(w_, m##I.z, acc.z);                                        \
        acc.w = fmaf(w_, m##I.w, acc.w);                                        \
    }

__global__ __launch_bounds__(256) void fused_layer(const float* __restrict__ H,
                                                   const float* __restrict__ W,
                                                   const float* __restrict__ bias,
                                                   float* __restrict__ OUT,
                                                   const int* __restrict__ rowptr,
                                                   const int* __restrict__ degi,
                                                   const int2* __restrict__ csr_sw,
                                                   const float* __restrict__ dis,
                                                   int n, int relu) {
    __shared__ float xs[FDIM * 32];                 // group-swizzled transposed tile
    __shared__ __align__(16) float ws[2][16][128];  // W chunk double buffer
    int t = threadIdx.x;
    int lane = t & 63;
    int wv = t >> 6;        // wave 0..3
    int half = lane >> 5;   // which edge of the pair
    int q = lane & 31;      // feature quarter: features q*4 .. q*4+3
    int q7 = q & 7;
    int rowBase = blockIdx.x * 32;

    // ---- Phase 1: aggregate 8 nodes per wave ----
    for (int i = 0; i < 8; i++) {
        int r = wv * 8 + i;
        int v = rowBase + r;
        float4 acc = make_float4(0.f, 0.f, 0.f, 0.f);
        if (v < n) {
            const int2* sw = csr_sw + rowptr[v];
            int cnt = (degi[v] + 3) & ~3;   // padded, multiple of 4
            int e = 0;
            for (; e + 16 <= cnt; e += 16) {   // 8 instrs, 16 edges
                PGATH(0, e) PGATH(1, e) PGATH(2, e) PGATH(3, e)
                PGATH(4, e) PGATH(5, e) PGATH(6, e) PGATH(7, e)
                PFMA(0) PFMA(1) PFMA(2) PFMA(3) PFMA(4) PFMA(5) PFMA(6) PFMA(7)
            }
            if (e + 8 <= cnt) {
                PGATH(0, e) PGATH(1, e) PGATH(2, e) PGATH(3, e)
                PFMA(0) PFMA(1) PFMA(2) PFMA(3)
                e += 8;
            }
            if (e + 4 <= cnt) {
                PGATH(0, e) PGATH(1, e)
                PFMA(0) PFMA(1)
            }
            // merge the two halves
            acc.x += __shfl_xor(acc.x, 32);
            acc.y += __shfl_xor(acc.y, 32);
            acc.z += __shfl_xor(acc.z, 32);
            acc.w += __shfl_xor(acc.w, 32);
            // self-loop term ns*h_v
            float dv = dis[v];
            float ns = dv * dv;
            float4 hv = *(const float4*)(H + (size_t)v * FDIM + q * 4);
            acc.x = fmaf(ns, hv.x, acc.x);
            acc.y = fmaf(ns, hv.y, acc.y);
            acc.z = fmaf(ns, hv.z, acc.z);
            acc.w = fmaf(ns, hv.w, acc.w);
        }
        if (half == 0) {   // features 4q..4q+3 of node r, group-swizzled col
            int col = 4 * ((r >> 2) ^ q7) + (r & 3);
            xs[(q * 4 + 0) * 32 + col] = acc.x;
            xs[(q * 4 + 1) * 32 + col] = acc.y;
            xs[(q * 4 + 2) * 32 + col] = acc.z;
            xs[(q * 4 + 3) * 32 + col] = acc.w;
        }
    }

    // ---- Phase 2: (agg)W + b, 4x4 micro-tile, pipelined ws chunks of 16 k ----
    int ti = t & 7;      // row group: nodes ti*4 .. ti*4+3
    int tj = t >> 3;     // col group: cols tj*4 .. tj*4+3
    int c4 = t & 31, kr = t >> 5;   // staging role: col-quad 0..31, row 0..7
    float acc2[4][4];
#pragma unroll
    for (int r = 0; r < 4; r++)
#pragma unroll
        for (int c = 0; c < 4; c++) acc2[r][c] = 0.f;

    // prologue: stage chunk 0 (k rows 0..15)
    {
        float4 w0 = *(const float4*)(W + (size_t)(kr)*FDIM + c4 * 4);
        float4 w1 = *(const float4*)(W + (size_t)(kr + 8) * FDIM + c4 * 4);
        *(float4*)&ws[0][kr][c4 * 4] = w0;
        *(float4*)&ws[0][kr + 8][c4 * 4] = w1;
    }
    __syncthreads();   // covers xs writes AND ws[0]

    for (int c = 0; c < 8; c++) {
        // issue next-chunk loads early (latency hides under the FMA block)
        float4 nw0, nw1;
        if (c < 7) {
            nw0 = *(const float4*)(W + (size_t)(16 * (c + 1) + kr) * FDIM + c4 * 4);
            nw1 = *(const float4*)(W + (size_t)(16 * (c + 1) + kr + 8) * FDIM + c4 * 4);
        }
        int buf = c & 1;
#pragma unroll
        for (int k = 0; k < 16; k++) {
            int kk = c * 16 + k;
            int swz = (kk >> 2) & 7;
            float4 a = *(const float4*)&xs[kk * 32 + 4 * (ti ^ swz)];
            float4 b = *(const float4*)&ws[buf][k][tj * 4];
            float ar[4] = {a.x, a.y, a.z, a.w};
            float br[4] = {b.x, b.y, b.z, b.w};
#pragma unroll
            for (int r = 0; r < 4; r++)
#pragma unroll
                for (int cc = 0; cc < 4; cc++) acc2[r][cc] = fmaf(ar[r], br[cc], acc2[r][cc]);
        }
        if (c < 7) {
            *(float4*)&ws[buf ^ 1][kr][c4 * 4] = nw0;
            *(float4*)&ws[buf ^ 1][kr + 8][c4 * 4] = nw1;
        }
        __syncthreads();
    }

    float4 bb = *(const float4*)(bias + tj * 4);
#pragma unroll
    for (int rr = 0; rr < 4; rr++) {
        int grow = rowBase + ti * 4 + rr;
        if (grow < n) {
            float4 o;
            o.x = acc2[rr][0] + bb.x;
            o.y = acc2[rr][1] + bb.y;
            o.z = acc2[rr][2] + bb.z;
            o.w = acc2[rr][3] + bb.w;
            if (relu) {
                o.x = fmaxf(o.x, 0.f); o.y = fmaxf(o.y, 0.f);
                o.z = fmaxf(o.z, 0.f); o.w = fmaxf(o.w, 0.f);
            }
            *(float4*)(OUT + (size_t)grow * FDIM + tj * 4) = o;
        }
    }
}

// ---------------------------------------------------------------------------
// Pooling: batch[] is SORTED. Segmented reduce, one atomic per boundary.
// ---------------------------------------------------------------------------

#define POOL_BLOCKS 2048

__global__ __launch_bounds__(128) void pool_kernel(const float* __restrict__ H,
                                                   const int* __restrict__ batch,
                                                   float* __restrict__ psum,
                                                   float* __restrict__ pcnt, int n) {
    int t = threadIdx.x;
    int chunk = (n + POOL_BLOCKS - 1) / POOL_BLOCKS;
    int lo = blockIdx.x * chunk;
    int hi = lo + chunk; if (hi > n) hi = n;
    if (lo >= hi) return;

    float acc = 0.f;
    int cnt = 0;
    int curg = batch[lo];
    float hv = H[(size_t)lo * FDIM + t];
    int g = curg;
    for (int v = lo; v < hi; v++) {
        float hcur = hv;
        int gcur = g;
        if (v + 1 < hi) {
            hv = H[(size_t)(v + 1) * FDIM + t];
            g = batch[v + 1];
        }
        if (gcur != curg) {
            atomicAdd(&psum[curg * FDIM + t], acc);
            if (t == 0) atomicAdd(&pcnt[curg], (float)cnt);
            acc = 0.f; cnt = 0; curg = gcur;
        }
        acc += hcur;
        cnt++;
    }
    atomicAdd(&psum[curg * FDIM + t], acc);
    if (t == 0) atomicAdd(&pcnt[curg], (float)cnt);
}

__global__ void final_lin(const float* __restrict__ psum, const float* __restrict__ pcnt,
                          const float* __restrict__ Wl, const float* __restrict__ bl,
                          float* __restrict__ out) {
    int t = blockIdx.x * blockDim.x + threadIdx.x;
    if (t >= N_GRAPHS * N_CLASSES) return;
    int g = t >> 5, c = t & 31;
    float inv = 1.0f / fmaxf(pcnt[g], 1.0f);
    float s = 0.f;
    for (int k = 0; k < FDIM; k++) s = fmaf(psum[g * FDIM + k], Wl[k * N_CLASSES + c], s);
    out[t] = s * inv + bl[c];
}

// ---------------------------------------------------------------------------

static inline size_t align256(size_t x) { return (x + 255) & ~(size_t)255; }

extern "C" void kernel_launch(void* const* d_in, const int* in_sizes, int n_in,
                              void* d_out, int out_size, void* d_ws, size_t ws_size,
                              hipStream_t stream) {
    const float* x     = (const float*)d_in[0];
    const int*   ei    = (const int*)d_in[1];
    const int*   batch = (const int*)d_in[2];
    const float* Wls[5] = {(const float*)d_in[3], (const float*)d_in[5], (const float*)d_in[7],
                           (const float*)d_in[9], (const float*)d_in[11]};
    const float* bls[5] = {(const float*)d_in[4], (const float*)d_in[6], (const float*)d_in[8],
                           (const float*)d_in[10], (const float*)d_in[12]};
    const float* W_lin = (const float*)d_in[13];
    const float* b_lin = (const float*)d_in[14];
    float* out = (float*)d_out;

    const int N = N_NODES, E = N_EDGES;
    const int* src = ei;
    const int* dst = ei + E;

    // workspace layout: zeroed arrays (deg,fill,psum,pcnt) laid out contiguously
    char* p = (char*)d_ws;
    size_t off = 0;
    float* hA = (float*)(p + off); off = align256(off + (size_t)N * FDIM * 4);
    float* hB = (float*)(p + off); off = align256(off + (size_t)N * FDIM * 4);
    int2*  csr_sw = (int2*)(p + off); off = align256(off + ((size_t)E + 4 * N) * 8);
    float* dis = (float*)(p + off); off = align256(off + (size_t)N * 4);
    int*   rowptr = (int*)(p + off); off = align256(off + (size_t)N * 4);
    int*   part = (int*)(p + off); off = align256(off + 512);
    size_t zero_off = off;
    int*   deg = (int*)(p + off); off = align256(off + (size_t)N * 4);
    int*   fill = (int*)(p + off); off = align256(off + (size_t)N * 4);
    float* psum = (float*)(p + off); off = align256(off + (size_t)N_GRAPHS * FDIM * 4);
    float* pcnt = (float*)(p + off); off = align256(off + (size_t)N_GRAPHS * 4);
    size_t zero_bytes = off - zero_off;
    (void)ws_size; (void)n_in; (void)in_sizes; (void)out_size;

    hipMemsetAsync(p + zero_off, 0, zero_bytes, stream);

    // preprocessing
    deg_kernel<<<(E + 255) / 256, 256, 0, stream>>>(dst, deg, E);
    int nChunks = (N + 511) / 512;  // 98
    scan_partial<<<nChunks, 512, 0, stream>>>(deg, part, dis, N);
    scan_offsets<<<1, 64, 0, stream>>>(part, nChunks);
    scan_final<<<nChunks, 512, 0, stream>>>(deg, part, rowptr, N);
    fill_csr<<<(E + 255) / 256, 256, 0, stream>>>(src, dst, rowptr, fill, dis,
                                                  csr_sw, E);
    pad_csr<<<(N + 255) / 256, 256, 0, stream>>>(deg, rowptr, csr_sw, N);

    // 5 fused GCN layers: h_{l+1} = relu(((A+nsI) h_l) W_l + b_l)
    int fusedBlocks = (N + 31) / 32;   // 1563
    const float* cur = x;
    float* bufs[2] = {hA, hB};
    for (int l = 0; l < 5; l++) {
        float* dst_h = bufs[l & 1];
        int relu = (l < 4) ? 1 : 0;
        fused_layer<<<fusedBlocks, 256, 0, stream>>>(cur, Wls[l], bls[l], dst_h,
                                                     rowptr, deg, csr_sw, dis, N, relu);
        cur = dst_h;
    }

    // pooling + classifier (final h is hA: layers 0,2,4 wrote hA)
    pool_kernel<<<POOL_BLOCKS, 128, 0, stream>>>(hA, batch, psum, pcnt, N);
    final_lin<<<(N_GRAPHS * N_CLASSES + 255) / 256, 256, 0, stream>>>(psum, pcnt, W_lin,
                                                                      b_lin, out);
}

// Round 17
// 419.720 us; speedup vs baseline: 1.1393x; 1.1393x over previous
//
#include <hip/hip_runtime.h>
#include <hip/hip_bf16.h>

#define N_NODES   50000
#define N_EDGES   500000
#define FDIM      128
#define N_CLASSES 32
#define N_GRAPHS  64

// ---------------------------------------------------------------------------
// Preprocessing: degree count, prefix scan over PADDED degrees (pad to x4),
// CSR fill + dummy self-edge padding (w=0).
// ---------------------------------------------------------------------------

__global__ void deg_kernel(const int* __restrict__ dst, int* __restrict__ deg, int E) {
    int e = blockIdx.x * blockDim.x + threadIdx.x;
    if (e < E) atomicAdd(&deg[dst[e]], 1);
}

__global__ void scan_partial(const int* __restrict__ deg, int* __restrict__ part,
                             float* __restrict__ dis, int n) {
    __shared__ int s[512];
    int t = threadIdx.x;
    int i = blockIdx.x * 512 + t;
    int d = (i < n) ? deg[i] : 0;
    if (i < n) dis[i] = rsqrtf((float)d + 1.0f);
    s[t] = (i < n) ? ((d + 3) & ~3) : 0;
    __syncthreads();
    for (int o = 256; o > 0; o >>= 1) {
        if (t < o) s[t] += s[t + o];
        __syncthreads();
    }
    if (t == 0) part[blockIdx.x] = s[0];
}

// parallel exclusive scan of <=128 partials in ONE block (was: serial 1-thread
// walk with ~98 dependent global loads ~= 15-20us; now ~2us)
__global__ void scan_offsets(int* part, int nb) {
    __shared__ int s[128];
    int t = threadIdx.x;
    int v = (t < nb) ? part[t] : 0;
    s[t] = v;
    __syncthreads();
    for (int o = 1; o < 128; o <<= 1) {
        int x = (t >= o) ? s[t - o] : 0;
        __syncthreads();
        s[t] += x;
        __syncthreads();
    }
    if (t < nb) part[t] = s[t] - v;   // exclusive
}

__global__ void scan_final(const int* __restrict__ deg, const int* __restrict__ part,
                           int* __restrict__ rowptr, int n) {
    __shared__ int s[512];
    int t = threadIdx.x;
    int i = blockIdx.x * 512 + t;
    int v = (i < n) ? ((deg[i] + 3) & ~3) : 0;
    s[t] = v;
    __syncthreads();
    for (int o = 1; o < 512; o <<= 1) {
        int x = (t >= o) ? s[t - o] : 0;
        __syncthreads();
        s[t] += x;
        __syncthreads();
    }
    if (i < n) rowptr[i] = part[blockIdx.x] + s[t] - v;   // exclusive (padded)
}

__global__ void fill_csr(const int* __restrict__ src, const int* __restrict__ dst,
                         const int* __restrict__ rowptr, int* __restrict__ fill,
                         const float* __restrict__ dis,
                         int2* __restrict__ csr_sw, int E) {
    int e = blockIdx.x * blockDim.x + threadIdx.x;
    if (e >= E) return;
    int d = dst[e], s = src[e];
    int pos = rowptr[d] + atomicAdd(&fill[d], 1);
    float w = dis[s] * dis[d];
    csr_sw[pos] = make_int2(s, __float_as_int(w));
}

__global__ void pad_csr(const int* __restrict__ deg, const int* __restrict__ rowptr,
                        int2* __restrict__ csr_sw, int n) {
    int v = blockIdx.x * blockDim.x + threadIdx.x;
    if (v >= n) return;
    int d = deg[v], dp = (d + 3) & ~3;
    int base = rowptr[v];
    for (int i = d; i < dp; i++) csr_sw[base + i] = make_int2(v, 0);
}

// ---------------------------------------------------------------------------
// Fused GCN layer (R15-proven best clean config): OUT = relu(((A+nsI)H)W + b)
// 256t, 8 nodes/wave gather, group-swizzled xs, single-staged ws[32][128].
// LDS = 16 + 16 = 32 KB.
// ---------------------------------------------------------------------------

#define PGATH(I, EBASE)                                                         \
    int2 p##I = sw[(EBASE) + 2 * (I) + half];                                   \
    float4 m##I = *(const float4*)(H + (size_t)p##I.x * FDIM + q * 4);

#define PFMA(I)                                                                 \
    {                                                                           \
        float w_ = __int_as_float(p##I.y);                                      \
        acc.x = fmaf(w_, m##I.x, acc.x);                                        \
        acc.y = fmaf(w_, m##I.y, acc.y);                                        \
        acc.z = fmaf(w_, m##I.z, acc.z);                                        \
        acc.w = fmaf(w_, m##I.w, acc.w);                                        \
    }

__global__ __launch_bounds__(256) void fused_layer(const float* __restrict__ H,
                                                   const float* __restrict__ W,
                                                   const float* __restrict__ bias,
                                                   float* __restrict__ OUT,
                                                   const int* __restrict__ rowptr,
                                                   const int* __restrict__ degi,
                                                   const int2* __restrict__ csr_sw,
                                                   const float* __restrict__ dis,
                                                   int n, int relu) {
    __shared__ float xs[FDIM * 32];              // group-swizzled transposed tile
    __shared__ __align__(16) float ws[32][128];  // W K-chunk, unpadded
    int t = threadIdx.x;
    int lane = t & 63;
    int wv = t >> 6;        // wave 0..3
    int half = lane >> 5;   // which edge of the pair
    int q = lane & 31;      // feature quarter: features q*4 .. q*4+3
    int q7 = q & 7;
    int rowBase = blockIdx.x * 32;

    // ---- Phase 1: aggregate 8 nodes per wave ----
    for (int i = 0; i < 8; i++) {
        int r = wv * 8 + i;
        int v = rowBase + r;
        float4 acc = make_float4(0.f, 0.f, 0.f, 0.f);
        if (v < n) {
            const int2* sw = csr_sw + rowptr[v];
            int cnt = (degi[v] + 3) & ~3;   // padded, multiple of 4
            int e = 0;
            for (; e + 16 <= cnt; e += 16) {   // 8 instrs, 16 edges
                PGATH(0, e) PGATH(1, e) PGATH(2, e) PGATH(3, e)
                PGATH(4, e) PGATH(5, e) PGATH(6, e) PGATH(7, e)
                PFMA(0) PFMA(1) PFMA(2) PFMA(3) PFMA(4) PFMA(5) PFMA(6) PFMA(7)
            }
            if (e + 8 <= cnt) {
                PGATH(0, e) PGATH(1, e) PGATH(2, e) PGATH(3, e)
                PFMA(0) PFMA(1) PFMA(2) PFMA(3)
                e += 8;
            }
            if (e + 4 <= cnt) {
                PGATH(0, e) PGATH(1, e)
                PFMA(0) PFMA(1)
            }
            // merge the two halves
            acc.x += __shfl_xor(acc.x, 32);
            acc.y += __shfl_xor(acc.y, 32);
            acc.z += __shfl_xor(acc.z, 32);
            acc.w += __shfl_xor(acc.w, 32);
            // self-loop term ns*h_v
            float dv = dis[v];
            float ns = dv * dv;
            float4 hv = *(const float4*)(H + (size_t)v * FDIM + q * 4);
            acc.x = fmaf(ns, hv.x, acc.x);
            acc.y = fmaf(ns, hv.y, acc.y);
            acc.z = fmaf(ns, hv.z, acc.z);
            acc.w = fmaf(ns, hv.w, acc.w);
        }
        if (half == 0) {   // features 4q..4q+3 of node r, group-swizzled col
            int col = 4 * ((r >> 2) ^ q7) + (r & 3);
            xs[(q * 4 + 0) * 32 + col] = acc.x;
            xs[(q * 4 + 1) * 32 + col] = acc.y;
            xs[(q * 4 + 2) * 32 + col] = acc.z;
            xs[(q * 4 + 3) * 32 + col] = acc.w;
        }
    }

    // ---- Phase 2: (agg)W + b, 4x4 micro-tile, ws staged in LDS ----
    int ti = t & 7;      // row group: nodes ti*4 .. ti*4+3
    int tj = t >> 3;     // col group: cols tj*4 .. tj*4+3
    float acc2[4][4];
#pragma unroll
    for (int r = 0; r < 4; r++)
#pragma unroll
        for (int c = 0; c < 4; c++) acc2[r][c] = 0.f;

    for (int k0 = 0; k0 < 128; k0 += 32) {
        __syncthreads();   // first iter covers xs writes; later: ws reuse
        {
            int c4 = t & 31, kr = t >> 5;   // kr 0..7
#pragma unroll
            for (int p = 0; p < 4; p++) {
                int k = kr + 8 * p;
                float4 v = *(const float4*)(W + (size_t)(k0 + k) * FDIM + c4 * 4);
                *(float4*)&ws[k][c4 * 4] = v;
            }
        }
        __syncthreads();
#pragma unroll 8
        for (int k = 0; k < 32; k++) {
            int kk = k0 + k;
            int swz = (kk >> 2) & 7;
            float4 a = *(const float4*)&xs[kk * 32 + 4 * (ti ^ swz)];
            float4 b = *(const float4*)&ws[k][tj * 4];
            float ar[4] = {a.x, a.y, a.z, a.w};
            float br[4] = {b.x, b.y, b.z, b.w};
#pragma unroll
            for (int r = 0; r < 4; r++)
#pragma unroll
                for (int c = 0; c < 4; c++) acc2[r][c] = fmaf(ar[r], br[c], acc2[r][c]);
        }
    }

    float4 bb = *(const float4*)(bias + tj * 4);
#pragma unroll
    for (int rr = 0; rr < 4; rr++) {
        int grow = rowBase + ti * 4 + rr;
        if (grow < n) {
            float4 o;
            o.x = acc2[rr][0] + bb.x;
            o.y = acc2[rr][1] + bb.y;
            o.z = acc2[rr][2] + bb.z;
            o.w = acc2[rr][3] + bb.w;
            if (relu) {
                o.x = fmaxf(o.x, 0.f); o.y = fmaxf(o.y, 0.f);
                o.z = fmaxf(o.z, 0.f); o.w = fmaxf(o.w, 0.f);
            }
            *(float4*)(OUT + (size_t)grow * FDIM + tj * 4) = o;
        }
    }
}

// ---------------------------------------------------------------------------
// Pooling: batch[] is SORTED. Segmented reduce, one atomic per boundary.
// ---------------------------------------------------------------------------

#define POOL_BLOCKS 2048

__global__ __launch_bounds__(128) void pool_kernel(const float* __restrict__ H,
                                                   const int* __restrict__ batch,
                                                   float* __restrict__ psum,
                                                   float* __restrict__ pcnt, int n) {
    int t = threadIdx.x;
    int chunk = (n + POOL_BLOCKS - 1) / POOL_BLOCKS;
    int lo = blockIdx.x * chunk;
    int hi = lo + chunk; if (hi > n) hi = n;
    if (lo >= hi) return;

    float acc = 0.f;
    int cnt = 0;
    int curg = batch[lo];
    float hv = H[(size_t)lo * FDIM + t];
    int g = curg;
    for (int v = lo; v < hi; v++) {
        float hcur = hv;
        int gcur = g;
        if (v + 1 < hi) {
            hv = H[(size_t)(v + 1) * FDIM + t];
            g = batch[v + 1];
        }
        if (gcur != curg) {
            atomicAdd(&psum[curg * FDIM + t], acc);
            if (t == 0) atomicAdd(&pcnt[curg], (float)cnt);
            acc = 0.f; cnt = 0; curg = gcur;
        }
        acc += hcur;
        cnt++;
    }
    atomicAdd(&psum[curg * FDIM + t], acc);
    if (t == 0) atomicAdd(&pcnt[curg], (float)cnt);
}

__global__ void final_lin(const float* __restrict__ psum, const float* __restrict__ pcnt,
                          const float* __restrict__ Wl, const float* __restrict__ bl,
                          float* __restrict__ out) {
    int t = blockIdx.x * blockDim.x + threadIdx.x;
    if (t >= N_GRAPHS * N_CLASSES) return;
    int g = t >> 5, c = t & 31;
    float inv = 1.0f / fmaxf(pcnt[g], 1.0f);
    float s = 0.f;
    for (int k = 0; k < FDIM; k++) s = fmaf(psum[g * FDIM + k], Wl[k * N_CLASSES + c], s);
    out[t] = s * inv + bl[c];
}

// ---------------------------------------------------------------------------

static inline size_t align256(size_t x) { return (x + 255) & ~(size_t)255; }

extern "C" void kernel_launch(void* const* d_in, const int* in_sizes, int n_in,
                              void* d_out, int out_size, void* d_ws, size_t ws_size,
                              hipStream_t stream) {
    const float* x     = (const float*)d_in[0];
    const int*   ei    = (const int*)d_in[1];
    const int*   batch = (const int*)d_in[2];
    const float* Wls[5] = {(const float*)d_in[3], (const float*)d_in[5], (const float*)d_in[7],
                           (const float*)d_in[9], (const float*)d_in[11]};
    const float* bls[5] = {(const float*)d_in[4], (const float*)d_in[6], (const float*)d_in[8],
                           (const float*)d_in[10], (const float*)d_in[12]};
    const float* W_lin = (const float*)d_in[13];
    const float* b_lin = (const float*)d_in[14];
    float* out = (float*)d_out;

    const int N = N_NODES, E = N_EDGES;
    const int* src = ei;
    const int* dst = ei + E;

    // workspace layout: zeroed arrays (deg,fill,psum,pcnt) laid out contiguously
    char* p = (char*)d_ws;
    size_t off = 0;
    float* hA = (float*)(p + off); off = align256(off + (size_t)N * FDIM * 4);
    float* hB = (float*)(p + off); off = align256(off + (size_t)N * FDIM * 4);
    int2*  csr_sw = (int2*)(p + off); off = align256(off + ((size_t)E + 4 * N) * 8);
    float* dis = (float*)(p + off); off = align256(off + (size_t)N * 4);
    int*   rowptr = (int*)(p + off); off = align256(off + (size_t)N * 4);
    int*   part = (int*)(p + off); off = align256(off + 512);
    size_t zero_off = off;
    int*   deg = (int*)(p + off); off = align256(off + (size_t)N * 4);
    int*   fill = (int*)(p + off); off = align256(off + (size_t)N * 4);
    float* psum = (float*)(p + off); off = align256(off + (size_t)N_GRAPHS * FDIM * 4);
    float* pcnt = (float*)(p + off); off = align256(off + (size_t)N_GRAPHS * 4);
    size_t zero_bytes = off - zero_off;
    (void)ws_size; (void)n_in; (void)in_sizes; (void)out_size;

    hipMemsetAsync(p + zero_off, 0, zero_bytes, stream);

    // preprocessing
    deg_kernel<<<(E + 255) / 256, 256, 0, stream>>>(dst, deg, E);
    int nChunks = (N + 511) / 512;  // 98
    scan_partial<<<nChunks, 512, 0, stream>>>(deg, part, dis, N);
    scan_offsets<<<1, 128, 0, stream>>>(part, nChunks);
    scan_final<<<nChunks, 512, 0, stream>>>(deg, part, rowptr, N);
    fill_csr<<<(E + 255) / 256, 256, 0, stream>>>(src, dst, rowptr, fill, dis,
                                                  csr_sw, E);
    pad_csr<<<(N + 255) / 256, 256, 0, stream>>>(deg, rowptr, csr_sw, N);

    // 5 fused GCN layers: h_{l+1} = relu(((A+nsI) h_l) W_l + b_l)
    int fusedBlocks = (N + 31) / 32;   // 1563
    const float* cur = x;
    float* bufs[2] = {hA, hB};
    for (int l = 0; l < 5; l++) {
        float* dst_h = bufs[l & 1];
        int relu = (l < 4) ? 1 : 0;
        fused_layer<<<fusedBlocks, 256, 0, stream>>>(cur, Wls[l], bls[l], dst_h,
                                                     rowptr, deg, csr_sw, dis, N, relu);
        cur = dst_h;
    }

    // pooling + classifier (final h is hA: layers 0,2,4 wrote hA)
    pool_kernel<<<POOL_BLOCKS, 128, 0, stream>>>(hA, batch, psum, pcnt, N);
    final_lin<<<(N_GRAPHS * N_CLASSES + 255) / 256, 256, 0, stream>>>(psum, pcnt, W_lin,
                                                                      b_lin, out);
}